// Round 12
// baseline (241.387 us; speedup 1.0000x reference)
//
#include <hip/hip_runtime.h>
#include <stdint.h>

#define NB 4096   // query rows
#define NM 8192   // memory rows
#define ND 1024   // feature dim

typedef __attribute__((ext_vector_type(8))) short bf16x8;
typedef __attribute__((ext_vector_type(4))) float f32x4;
typedef __attribute__((ext_vector_type(8))) unsigned short u16x8;

static __device__ __forceinline__ unsigned short f2bf(float f) {
  union { float f; uint32_t u; } v; v.f = f;
  uint32_t u = v.u;
  u += 0x7fffu + ((u >> 16) & 1u);   // RNE
  return (unsigned short)(u >> 16);
}
static __device__ __forceinline__ float bf2f(unsigned short b) {
  union { uint32_t u; float f; } v; v.u = ((uint32_t)b) << 16; return v.f;
}

static __device__ __forceinline__ void gload_lds16(const void* g, void* l) {
  __builtin_amdgcn_global_load_lds(
      (__attribute__((address_space(1))) void*)g,
      (__attribute__((address_space(3))) void*)l, 16, 0, 0);
}

#define BAR()   __builtin_amdgcn_s_barrier()
#define LGKM8() asm volatile("s_waitcnt lgkmcnt(8)" ::: "memory")
#define LGKM4() asm volatile("s_waitcnt lgkmcnt(4)" ::: "memory")
#define VMC8()  asm volatile("s_waitcnt vmcnt(8)" ::: "memory")
#define VMC0()  asm volatile("s_waitcnt vmcnt(0)" ::: "memory")

// ---- L2-normalize rows of x [rows x 1024] fp32 -> bf16 out -----------------
__global__ void nrm_kernel(const float* __restrict__ x, unsigned short* __restrict__ out) {
  const int row = blockIdx.x, t = threadIdx.x;
  const float4 v = ((const float4*)(x + (size_t)row * ND))[t];
  float ss = v.x * v.x + v.y * v.y + v.z * v.z + v.w * v.w;
  #pragma unroll
  for (int o = 32; o > 0; o >>= 1) ss += __shfl_xor(ss, o);
  __shared__ float red[4];
  if ((t & 63) == 0) red[t >> 6] = ss;
  __syncthreads();
  ss = (red[0] + red[1]) + (red[2] + red[3]);
  const float sc = 1.0f / fmaxf(sqrtf(ss), 1e-12f);
  ushort4 o4;
  o4.x = f2bf(v.x * sc); o4.y = f2bf(v.y * sc);
  o4.z = f2bf(v.z * sc); o4.w = f2bf(v.w * sc);
  ((ushort4*)(out + (size_t)row * ND))[t] = o4;
}

// ---- transpose memn [8192x1024] bf16 -> memt [1024x8192] bf16 --------------
__global__ void tr_kernel(const unsigned short* __restrict__ memn, unsigned short* __restrict__ memt) {
  __shared__ unsigned short Ts[64][66];
  const int t = threadIdx.x;
  const int d0 = blockIdx.x * 64, m0 = blockIdx.y * 64;
  #pragma unroll
  for (int r = 0; r < 2; ++r) {
    const int lrow = r * 32 + (t >> 3);
    const int lcol = (t & 7) * 8;
    u16x8 v = *(const u16x8*)(memn + (size_t)(m0 + lrow) * ND + d0 + lcol);
    #pragma unroll
    for (int j = 0; j < 8; ++j) Ts[lcol + j][lrow] = v[j];
  }
  __syncthreads();
  #pragma unroll
  for (int r = 0; r < 2; ++r) {
    const int orow = r * 32 + (t >> 3);
    const int ocol = (t & 7) * 8;
    u16x8 o;
    #pragma unroll
    for (int j = 0; j < 8; ++j) o[j] = Ts[orow][ocol + j];
    *(u16x8*)(memt + (size_t)(d0 + orow) * NM + m0 + ocol) = o;
  }
}

// ==== 256x256 GEMM, counted-lgkm pipeline: loads 1 phase ahead of MFMA ======
// C[M,N] = A[M,K] * B[N,K]^T (both bf16 row-major, ld = K stride).
// 512 thr = 8 waves (2M x 4N), per-wave 128x64 out, BK=64, dbuf LDS 128 KiB.
// Swizzle: phys_cb = cb ^ ((row&7)<<4); pre-swizzled global src + ds_read.
// Fragment rows: A row = m*32 + wr*16 + lr; B row = nf*64 + wc*16 + lr.
// r12: COUNTED lgkm waits (never 0 in the loop). Each phase issues the NEXT
// quadrant's frag reads pre-cluster into DISJOINT regs, then waits only the
// older reads (lgkmcnt(N) excludes the just-issued batch). LDS pipe retires
// reads DURING the MFMA cluster; consumption is one phase later.
//   ph1: rd a1(p)[8];                 BAR; lgkm(8); Q1(a0,b0); BAR
//   ph2: rd b1(p)[4]; stg A0,B0(T+2); BAR; lgkm(4); Q2(a1,b0); VMC8; BAR
//   ph3: rd b0(q)[4]; stg A1(T+2);    BAR; lgkm(4); Q3(a1,b1); BAR
//   ph4: stg B1(T+2);                 BAR;          Q4(a0,b1); rd a0(q)[8]; VMC8; BAR
// vmcnt ledger (steady): ph2: 12 outstanding -> drain 4 oldest (= T+1's A0,B0);
// ph4: 12 -> drain T+1's A1,B1. Region-overwrite audit: every stage lands
// >= 1 completed-lgkm + barrier after its region's last ds_read (see waits).
// MODE 0: fp32 C partials (split-K).  MODE 1: E=exp(C) bf16 + psum row-sums.
template<int MODE>
__global__ __launch_bounds__(512, 2) void gemmcl(
    const unsigned short* __restrict__ A, const unsigned short* __restrict__ B,
    void* __restrict__ Cv, float* __restrict__ psum,
    int ld, int ldc, int mt, int tps, int kchunk, unsigned long long cstride)
{
  extern __shared__ char smem[];   // [buf][A 32K | B 32K] x2 = 128 KiB
  const int t = threadIdx.x;
  const int w = t >> 6, l = t & 63;
  const int wr = w >> 2, wc = w & 3;
  const int nwg = gridDim.x, cpx = nwg >> 3;
  const int id = (blockIdx.x & 7) * cpx + (blockIdx.x >> 3);  // XCD swizzle
  const int ksp = id / tps, rem = id % tps;
  const int brow = rem % mt, bcol = rem / mt;
  const int k0 = ksp * kchunk;
  const int nt = kchunk >> 6;          // K-tiles (even)

  const int srow = l >> 3;                       // staging row-in-8-group
  const int scol = ((l & 7) ^ srow) << 3;        // pre-swizzled global col
  const int lr = l & 15, lhi = l >> 4;
  const int swz = (l & 7) << 4;
  const int cbk0 = (lhi * 16) ^ swz;
  const int cbk1 = (64 + lhi * 16) ^ swz;
  const int aoffr = (wr * 16 + lr) * 128;        // + m*4096
  const int boffr = (wc * 16 + lr) * 128;        // + nf*8192

  const unsigned short* Ab = A + (size_t)(brow * 256 + w * 8 + srow) * ld + k0 + scol;
  const unsigned short* Bb = B + (size_t)(bcol * 256 + w * 8 + srow) * ld + k0 + scol;

  auto stageA = [&](int p, int h, int tau) {     // one half-tile = 2 gloads
    const int kt = (tau < nt ? tau : nt - 1) << 6;
    const unsigned short* g = Ab + (size_t)(h * 128) * ld + kt;
    char* d = smem + p * 65536 + h * 16384 + w * 1024;
    gload_lds16(g, d);
    gload_lds16(g + (size_t)64 * ld, d + 8192);
  };
  auto stageB = [&](int p, int h, int tau) {
    const int kt = (tau < nt ? tau : nt - 1) << 6;
    const unsigned short* g = Bb + (size_t)(h * 128) * ld + kt;
    char* d = smem + p * 65536 + 32768 + h * 16384 + w * 1024;
    gload_lds16(g, d);
    gload_lds16(g + (size_t)64 * ld, d + 8192);
  };
  auto ldA = [&](int p, int m, int kk) -> bf16x8 {   // A row m*32+wr*16+lr
    return *(const bf16x8*)(smem + p * 65536 + m * 4096 + aoffr + (kk ? cbk1 : cbk0));
  };
  auto ldB = [&](int p, int nf, int kk) -> bf16x8 {  // B row nf*64+wc*16+lr
    return *(const bf16x8*)(smem + p * 65536 + 32768 + nf * 8192 + boffr + (kk ? cbk1 : cbk0));
  };

  f32x4 acc[8][4] = {};
  bf16x8 a0[4][2], a1[4][2], b0[2][2], b1[2][2];

  #define CL(AF, BF, MO, NO)                                                   \
    __builtin_amdgcn_s_setprio(1);                                             \
    _Pragma("unroll")                                                          \
    for (int kk = 0; kk < 2; ++kk)                                             \
      _Pragma("unroll")                                                        \
      for (int m = 0; m < 4; ++m)                                              \
        _Pragma("unroll")                                                      \
        for (int n = 0; n < 2; ++n)                                            \
          acc[MO + m][NO + n] = __builtin_amdgcn_mfma_f32_16x16x32_bf16(       \
              AF[m][kk], BF[n][kk], acc[MO + m][NO + n], 0, 0, 0);             \
    __builtin_amdgcn_s_setprio(0);

  // prologue: stage T0 + T1 fully (order A0,B0,A1,B1 each); drain T0; preload
  // a0(p0), b0(p0). First ph1's lgkm(8) then waits these 12 prologue reads.
  stageA(0, 0, 0); stageB(0, 0, 0); stageA(0, 1, 0); stageB(0, 1, 0);
  stageA(1, 0, 1); stageB(1, 0, 1); stageA(1, 1, 1); stageB(1, 1, 1);
  VMC8();
  BAR();
  #pragma unroll
  for (int m = 0; m < 4; ++m) { a0[m][0] = ldA(0, m, 0); a0[m][1] = ldA(0, m, 1); }
  #pragma unroll
  for (int n = 0; n < 2; ++n) { b0[n][0] = ldB(0, n, 0); b0[n][1] = ldB(0, n, 1); }

  auto tile_body = [&](int p, int q, int tau2) {
    // ---- ph1: rd a1(p); BAR; lgkm(8); Q1(a0,b0)
    #pragma unroll
    for (int m = 0; m < 4; ++m) { a1[m][0] = ldA(p, 4 + m, 0); a1[m][1] = ldA(p, 4 + m, 1); }
    BAR(); LGKM8();
    CL(a0, b0, 0, 0);
    BAR();
    // ---- ph2: rd b1(p); stage A0+B0(T+2 into p); BAR; lgkm(4); Q2(a1,b0); VMC8
    #pragma unroll
    for (int n = 0; n < 2; ++n) { b1[n][0] = ldB(p, 2 + n, 0); b1[n][1] = ldB(p, 2 + n, 1); }
    stageA(p, 0, tau2); stageB(p, 0, tau2);
    BAR(); LGKM4();
    CL(a1, b0, 4, 0);
    VMC8();             // 12 outstanding -> drain T+1's A0,B0 (for ph3/ph4 reads)
    BAR();
    // ---- ph3: rd b0(q, next tile); stage A1(T+2); BAR; lgkm(4); Q3(a1,b1)
    #pragma unroll
    for (int n = 0; n < 2; ++n) { b0[n][0] = ldB(q, n, 0); b0[n][1] = ldB(q, n, 1); }
    stageA(p, 1, tau2);
    BAR(); LGKM4();
    CL(a1, b1, 4, 2);
    BAR();
    // ---- ph4: stage B1(T+2); BAR; Q4(a0,b1); rd a0(q, next); VMC8
    stageB(p, 1, tau2);
    BAR();
    CL(a0, b1, 0, 2);
    #pragma unroll
    for (int m = 0; m < 4; ++m) { a0[m][0] = ldA(q, m, 0); a0[m][1] = ldA(q, m, 1); }
    VMC8();             // 12 outstanding -> drain T+1's A1,B1 (for T+1.ph1/ph2)
    BAR();
  };

  const int niter = nt >> 1;
  for (int i = 0; i < niter; ++i) {
    tile_body(0, 1, 2 * i + 2);
    tile_body(1, 0, 2 * i + 3);
  }
  #undef CL

  // epilogue: C row = brow*256 + m*32 + wr*16 + lhi*4 + j,
  //           C col = bcol*256 + n*64 + wc*16 + lr     [m89/m91 C/D map]
  const int crow0 = brow * 256 + wr * 16 + lhi * 4;
  const int ccol0 = bcol * 256 + wc * 16 + lr;
  if constexpr (MODE == 1) {
    // E = exp(sim) bf16 + per-block row-sum partials (deterministic)
    unsigned short* Cp = (unsigned short*)Cv;
    float rs[8][4];
    #pragma unroll
    for (int m = 0; m < 8; ++m)
      #pragma unroll
      for (int j = 0; j < 4; ++j) rs[m][j] = 0.f;
    #pragma unroll
    for (int m = 0; m < 8; ++m)
      #pragma unroll
      for (int n = 0; n < 4; ++n)
        #pragma unroll
        for (int j = 0; j < 4; ++j) {
          const float e = __expf(acc[m][n][j]);
          rs[m][j] += e;
          Cp[(size_t)(crow0 + m * 32 + j) * ldc + ccol0 + n * 64] = f2bf(e);
        }
    #pragma unroll
    for (int m = 0; m < 8; ++m)
      #pragma unroll
      for (int j = 0; j < 4; ++j)
        #pragma unroll
        for (int o = 1; o < 16; o <<= 1) rs[m][j] += __shfl_xor(rs[m][j], o);
    VMC0();            // in-flight clamped stages still write smem
    __syncthreads();
    float* ls = (float*)smem;   // [wc][256 rows] = 4 KiB
    if (lr == 0) {
      #pragma unroll
      for (int m = 0; m < 8; ++m)
        #pragma unroll
        for (int j = 0; j < 4; ++j)
          ls[wc * 256 + wr * 16 + m * 32 + lhi * 4 + j] = rs[m][j];
    }
    __syncthreads();
    if (t < 256) {
      const float s4 = ls[t] + ls[256 + t] + ls[512 + t] + ls[768 + t];
      psum[(size_t)bcol * NB + brow * 256 + t] = s4;
    }
  } else {
    float* Cp = (float*)Cv + (unsigned long long)ksp * cstride;
    #pragma unroll
    for (int m = 0; m < 8; ++m)
      #pragma unroll
      for (int n = 0; n < 4; ++n)
        #pragma unroll
        for (int j = 0; j < 4; ++j)
          Cp[(size_t)(crow0 + m * 32 + j) * ldc + ccol0 + n * 64] = acc[m][n][j];
  }
}

// ---- scale: attn = E / s, s = sum of 32 col-block partials; also 1/s -------
__global__ void scale_kernel(const unsigned short* __restrict__ E,
                             const float* __restrict__ psum,
                             float* __restrict__ attn, float* __restrict__ sinv) {
  const int row = blockIdx.x, t = threadIdx.x;   // 256 thr
  __shared__ float sh;
  if (t < 64) {
    float p = (t < 32) ? psum[(size_t)t * NB + row] : 0.f;
    #pragma unroll
    for (int o = 16; o > 0; o >>= 1) p += __shfl_xor(p, o);
    if (t == 0) { sh = p; sinv[row] = 1.0f / p; }
  }
  __syncthreads();
  const float inv = 1.0f / sh;
  const unsigned short* erow = E + (size_t)row * NM;
  float* arow = attn + (size_t)row * NM;
  #pragma unroll
  for (int i = 0; i < 4; ++i) {
    u16x8 bv = ((const u16x8*)erow)[i * 256 + t];
    float4 f0, f1;
    #pragma unroll
    for (int j = 0; j < 8; ++j) {
      const float a = bf2f(bv[j]) * inv;
      if (j < 4) (&f0.x)[j] = a; else (&f1.x)[j - 4] = a;
    }
    const int e = (i * 256 + t) * 8;
    *(float4*)(arow + e) = f0;
    *(float4*)(arow + e + 4) = f1;
  }
}

// ---- reduce partials: mf = (sum_k part[k]) * sinv[row], S = 4 --------------
__global__ void reduce_kernel(const float4* __restrict__ part, float4* __restrict__ mf,
                              const float* __restrict__ sinv) {
  const size_t n4 = (size_t)NB * ND / 4;
  for (size_t i = (size_t)blockIdx.x * blockDim.x + threadIdx.x; i < n4;
       i += (size_t)gridDim.x * blockDim.x) {
    const float is = sinv[i >> 8];   // 256 float4 per row
    float4 s = part[i];
    #pragma unroll
    for (int k = 1; k < 4; ++k) {
      float4 p = part[(size_t)k * n4 + i];
      s.x += p.x; s.y += p.y; s.z += p.z; s.w += p.w;
    }
    s.x *= is; s.y *= is; s.z *= is; s.w *= is;
    mf[i] = s;
  }
}

extern "C" void kernel_launch(void* const* d_in, const int* in_sizes, int n_in,
                              void* d_out, int out_size, void* d_ws, size_t ws_size,
                              hipStream_t stream) {
  const float* q   = (const float*)d_in[0];
  const float* mem = (const float*)d_in[1];
  float* mf   = (float*)d_out;                       // [4096 x 1024]
  float* attn = (float*)d_out + (size_t)NB * ND;     // [4096 x 8192]
  char* ws = (char*)d_ws;
  unsigned short* qn   = (unsigned short*)(ws);                        // 8 MiB
  unsigned short* memn = (unsigned short*)(ws + ((size_t)8  << 20));   // 16 MiB
  unsigned short* memt = (unsigned short*)(ws + ((size_t)24 << 20));   // 16 MiB
  unsigned short* E    = (unsigned short*)(ws + ((size_t)40 << 20));   // 64 MiB
  float* psum          = (float*)(ws + ((size_t)104 << 20));           // 512 KiB
  float* sinv          = (float*)(ws + ((size_t)104 << 20) + (512 << 10)); // 16 KiB
  float* part          = (float*)(ws + ((size_t)105 << 20));           // 64 MiB

  hipFuncSetAttribute((const void*)gemmcl<1>,
                      hipFuncAttributeMaxDynamicSharedMemorySize, 131072);
  hipFuncSetAttribute((const void*)gemmcl<0>,
                      hipFuncAttributeMaxDynamicSharedMemorySize, 131072);

  hipLaunchKernelGGL(nrm_kernel, dim3(NM), dim3(256), 0, stream, mem, memn);
  hipLaunchKernelGGL(nrm_kernel, dim3(NB), dim3(256), 0, stream, q, qn);
  hipLaunchKernelGGL(tr_kernel, dim3(ND / 64, NM / 64), dim3(256), 0, stream, memn, memt);

  // E = exp(qn * memn^T) bf16 + psum : M=4096, N=8192, K=1024; 512 tiles.
  hipLaunchKernelGGL((gemmcl<1>), dim3((NB / 256) * (NM / 256)), dim3(512), 131072, stream,
                     qn, memn, (void*)E, psum, ND, NM, NB / 256,
                     (NB / 256) * (NM / 256), ND, 0ULL);

  // attn = E / s (fp32 out) + sinv
  hipLaunchKernelGGL(scale_kernel, dim3(NB), dim3(256), 0, stream, E, psum, attn, sinv);

  // part[k] = E * memt^T (k-slice) : M=4096, N=1024, K=8192, S=4 (kchunk 2048)
  const int tps = (NB / 256) * (ND / 256);   // 64
  hipLaunchKernelGGL((gemmcl<0>), dim3(tps * 4), dim3(512), 131072, stream,
                     E, memt, (void*)part, (float*)nullptr, NM, ND, NB / 256, tps, NM / 4,
                     (unsigned long long)NB * ND);
  hipLaunchKernelGGL(reduce_kernel, dim3(2048), dim3(256), 0, stream,
                     (const float4*)part, (float4*)mf, sinv);
}

// Round 13
// 228.940 us; speedup vs baseline: 1.0544x; 1.0544x over previous
//
#include <hip/hip_runtime.h>
#include <stdint.h>

#define NB 4096   // query rows
#define NM 8192   // memory rows
#define ND 1024   // feature dim

typedef __attribute__((ext_vector_type(8))) short bf16x8;
typedef __attribute__((ext_vector_type(4))) float f32x4;
typedef __attribute__((ext_vector_type(8))) unsigned short u16x8;

static __device__ __forceinline__ unsigned short f2bf(float f) {
  union { float f; uint32_t u; } v; v.f = f;
  uint32_t u = v.u;
  u += 0x7fffu + ((u >> 16) & 1u);   // RNE
  return (unsigned short)(u >> 16);
}
static __device__ __forceinline__ float bf2f(unsigned short b) {
  union { uint32_t u; float f; } v; v.u = ((uint32_t)b) << 16; return v.f;
}

static __device__ __forceinline__ void gload_lds16(const void* g, void* l) {
  __builtin_amdgcn_global_load_lds(
      (__attribute__((address_space(1))) void*)g,
      (__attribute__((address_space(3))) void*)l, 16, 0, 0);
}

#define BAR()   __builtin_amdgcn_s_barrier()
#define LGKM0() asm volatile("s_waitcnt lgkmcnt(0)" ::: "memory")
#define VMC0()  asm volatile("s_waitcnt vmcnt(0)" ::: "memory")

// ---- L2-normalize rows of x [rows x 1024] fp32 -> bf16 out -----------------
__global__ void nrm_kernel(const float* __restrict__ x, unsigned short* __restrict__ out) {
  const int row = blockIdx.x, t = threadIdx.x;
  const float4 v = ((const float4*)(x + (size_t)row * ND))[t];
  float ss = v.x * v.x + v.y * v.y + v.z * v.z + v.w * v.w;
  #pragma unroll
  for (int o = 32; o > 0; o >>= 1) ss += __shfl_xor(ss, o);
  __shared__ float red[4];
  if ((t & 63) == 0) red[t >> 6] = ss;
  __syncthreads();
  ss = (red[0] + red[1]) + (red[2] + red[3]);
  const float sc = 1.0f / fmaxf(sqrtf(ss), 1e-12f);
  ushort4 o4;
  o4.x = f2bf(v.x * sc); o4.y = f2bf(v.y * sc);
  o4.z = f2bf(v.z * sc); o4.w = f2bf(v.w * sc);
  ((ushort4*)(out + (size_t)row * ND))[t] = o4;
}

// ---- transpose memn [8192x1024] bf16 -> memt [1024x8192] bf16 --------------
__global__ void tr_kernel(const unsigned short* __restrict__ memn, unsigned short* __restrict__ memt) {
  __shared__ unsigned short Ts[64][66];
  const int t = threadIdx.x;
  const int d0 = blockIdx.x * 64, m0 = blockIdx.y * 64;
  #pragma unroll
  for (int r = 0; r < 2; ++r) {
    const int lrow = r * 32 + (t >> 3);
    const int lcol = (t & 7) * 8;
    u16x8 v = *(const u16x8*)(memn + (size_t)(m0 + lrow) * ND + d0 + lcol);
    #pragma unroll
    for (int j = 0; j < 8; ++j) Ts[lcol + j][lrow] = v[j];
  }
  __syncthreads();
  #pragma unroll
  for (int r = 0; r < 2; ++r) {
    const int orow = r * 32 + (t >> 3);
    const int ocol = (t & 7) * 8;
    u16x8 o;
    #pragma unroll
    for (int j = 0; j < 8; ++j) o[j] = Ts[orow][ocol + j];
    *(u16x8*)(memt + (size_t)(d0 + orow) * NM + m0 + ocol) = o;
  }
}

// ====== 256x256 GEMM with ANTI-PHASED WAVE GROUPS (m114 mechanism) ==========
// C[M,N] = A[M,K] * B[N,K]^T (both bf16 row-major, ld = K stride).
// 512 thr = 8 waves. Group g = w>>2 (round-robin wave->SIMD: each SIMD hosts
// one wave of each group). Groups split N: g covers cols g*128..+128; within
// a group, wave grid 2x2: wr=(w>>1)&1 (rows), wc=w&1 (64-col slab).
// Per-wave output 128x64 (acc 8x4 f32x4). BK=64, dbuf LDS 128 KiB.
// Swizzle: phys_cb = cb ^ ((row&7)<<4) (stage source + ds_read; 0 conflicts).
// SCHEDULE (r13): group g1 runs one phase behind g0, so EVERY barrier
// interval has 4 waves doing a 64-MFMA cluster and 4 waves doing ds_reads
// (1 of each per SIMD) -> matrix pipe and LDS pipe run concurrently.
//   tile T (p=T&1):
//     EVEN: g0: read frags(T, buf p) | g1: MFMA(T-1) ; all: stage T+1->buf p^1 ; BAR
//     ODD:  g0: MFMA(T)             | g1: read frags(T, buf p)
//           all: LGKM0 (readers' ds_reads drained before next-phase stage
//                overwrite) ; VMC0 (tile T+1 staged & drained block-wide,
//                age ~1.5 phases >= HBM latency) ; BAR
// Overwrite audit: buf p^1 prev tile last read odd(T-1); stage at even(T) is
// after that barrier. Tile-T reads all drained before even(T+1) stage. Safe.
// MODE 0: fp32 C partials (split-K).  MODE 1: E=exp(C) bf16 + psum row-sums.
template<int MODE>
__global__ __launch_bounds__(512, 2) void gemmag(
    const unsigned short* __restrict__ A, const unsigned short* __restrict__ B,
    void* __restrict__ Cv, float* __restrict__ psum,
    int ld, int ldc, int mt, int tps, int kchunk, unsigned long long cstride)
{
  extern __shared__ char smem[];   // [buf][A 32K | B 32K] x2 = 128 KiB
  const int t = threadIdx.x;
  const int w = t >> 6, l = t & 63;
  const int g = w >> 2, wr = (w >> 1) & 1, wc = w & 1;
  const bool rdr = (g == 0);
  const int nwg = gridDim.x, cpx = nwg >> 3;
  const int id = (blockIdx.x & 7) * cpx + (blockIdx.x >> 3);  // XCD swizzle
  const int ksp = id / tps, rem = id % tps;
  const int brow = rem % mt, bcol = rem / mt;
  const int k0 = ksp * kchunk;
  const int nt = kchunk >> 6;          // K-tiles

  const int srow = l >> 3;                       // staging row-in-8-group
  const int scol = ((l & 7) ^ srow) << 3;        // pre-swizzled global col
  const int lr = l & 15, lhi = l >> 4;
  const int swz = (l & 7) << 4;
  const int cbk0 = (lhi * 16) ^ swz;
  const int cbk1 = (64 + lhi * 16) ^ swz;
  const int aoffr = (wr * 16 + lr) * 128;                    // + m*4096
  const int boffr = (g * 128 + wc * 64 + lr) * 128;          // + nf*2048

  const unsigned short* Ab = A + (size_t)(brow * 256 + w * 8 + srow) * ld + k0 + scol;
  const unsigned short* Bb = B + (size_t)(bcol * 256 + w * 8 + srow) * ld + k0 + scol;

  auto stageA = [&](int p, int h, int tau) {     // one half-tile = 2 gloads
    const int kt = (tau < nt ? tau : nt - 1) << 6;
    const unsigned short* gp = Ab + (size_t)(h * 128) * ld + kt;
    char* d = smem + p * 65536 + h * 16384 + w * 1024;
    gload_lds16(gp, d);
    gload_lds16(gp + (size_t)64 * ld, d + 8192);
  };
  auto stageB = [&](int p, int h, int tau) {
    const int kt = (tau < nt ? tau : nt - 1) << 6;
    const unsigned short* gp = Bb + (size_t)(h * 128) * ld + kt;
    char* d = smem + p * 65536 + 32768 + h * 16384 + w * 1024;
    gload_lds16(gp, d);
    gload_lds16(gp + (size_t)64 * ld, d + 8192);
  };
  auto stage_tile = [&](int p, int tau) {
    stageA(p, 0, tau); stageA(p, 1, tau); stageB(p, 0, tau); stageB(p, 1, tau);
  };
  auto ldA = [&](int p, int m, int kk) -> bf16x8 {   // A row m*32 + wr*16 + lr
    return *(const bf16x8*)(smem + p * 65536 + m * 4096 + aoffr + (kk ? cbk1 : cbk0));
  };
  auto ldB = [&](int p, int nf, int kk) -> bf16x8 {  // B row g*128+wc*64+nf*16+lr
    return *(const bf16x8*)(smem + p * 65536 + 32768 + nf * 2048 + boffr + (kk ? cbk1 : cbk0));
  };

  f32x4 acc[8][4] = {};
  bf16x8 a[8][2], b[4][2];

  #define RD(P)                                                                \
    _Pragma("unroll")                                                          \
    for (int m = 0; m < 8; ++m) { a[m][0] = ldA(P, m, 0); a[m][1] = ldA(P, m, 1); } \
    _Pragma("unroll")                                                          \
    for (int n = 0; n < 4; ++n) { b[n][0] = ldB(P, n, 0); b[n][1] = ldB(P, n, 1); }

  #define CL64()                                                               \
    __builtin_amdgcn_s_setprio(1);                                             \
    _Pragma("unroll")                                                          \
    for (int kk = 0; kk < 2; ++kk)                                             \
      _Pragma("unroll")                                                        \
      for (int m = 0; m < 8; ++m)                                              \
        _Pragma("unroll")                                                      \
        for (int n = 0; n < 4; ++n)                                            \
          acc[m][n] = __builtin_amdgcn_mfma_f32_16x16x32_bf16(                 \
              a[m][kk], b[n][kk], acc[m][n], 0, 0, 0);                         \
    __builtin_amdgcn_s_setprio(0);

  // prologue: stage tile 0 into buf 0; drain fully.
  stage_tile(0, 0);
  VMC0();
  BAR();

  for (int T = 0; T < nt; ++T) {
    const int p = T & 1;
    // ---- EVEN phase: g0 reads T | g1 MFMAs T-1 ; stage T+1 -> buf p^1
    if (rdr) {
      RD(p);
    } else if (T > 0) {
      CL64();
    }
    stage_tile(p ^ 1, T + 1);
    BAR();
    // ---- ODD phase: g0 MFMAs T | g1 reads T
    if (rdr) {
      LGKM0();
      CL64();
    } else {
      RD(p);
    }
    LGKM0();   // readers' ds_reads drained before next-phase stage overwrite
    VMC0();    // tile T+1 staged & visible block-wide (age ~1.5 phases)
    BAR();
  }
  // epilogue MFMA for g1 (tile nt-1 frags are in its registers)
  if (!rdr) {
    CL64();
  }
  #undef RD
  #undef CL64

  // epilogue: C row = brow*256 + m*32 + wr*16 + lhi*4 + j,
  //           C col = bcol*256 + g*128 + wc*64 + n*16 + lr   [m89/m91 C/D map]
  const int crow0 = brow * 256 + wr * 16 + lhi * 4;
  const int ccol0 = bcol * 256 + g * 128 + wc * 64 + lr;
  if constexpr (MODE == 1) {
    // E = exp(sim) bf16 + per-block row-sum partials (deterministic)
    unsigned short* Cp = (unsigned short*)Cv;
    float rs[8][4];
    #pragma unroll
    for (int m = 0; m < 8; ++m)
      #pragma unroll
      for (int j = 0; j < 4; ++j) rs[m][j] = 0.f;
    #pragma unroll
    for (int m = 0; m < 8; ++m)
      #pragma unroll
      for (int n = 0; n < 4; ++n)
        #pragma unroll
        for (int j = 0; j < 4; ++j) {
          const float e = __expf(acc[m][n][j]);
          rs[m][j] += e;
          Cp[(size_t)(crow0 + m * 32 + j) * ldc + ccol0 + n * 16] = f2bf(e);
        }
    // 16-lane (lr) reduce -> lanes lr==0 hold this wave's 64-col sums
    #pragma unroll
    for (int m = 0; m < 8; ++m)
      #pragma unroll
      for (int j = 0; j < 4; ++j)
        #pragma unroll
        for (int o = 1; o < 16; o <<= 1) rs[m][j] += __shfl_xor(rs[m][j], o);
    VMC0();            // in-flight clamped stages still write smem
    __syncthreads();
    float* ls = (float*)smem;   // [q=g*2+wc][256 rows] = 4 KiB
    if (lr == 0) {
      const int q = g * 2 + wc;
      #pragma unroll
      for (int m = 0; m < 8; ++m)
        #pragma unroll
        for (int j = 0; j < 4; ++j)
          ls[q * 256 + wr * 16 + m * 32 + lhi * 4 + j] = rs[m][j];
    }
    __syncthreads();
    if (t < 256) {
      const float s4 = ls[t] + ls[256 + t] + ls[512 + t] + ls[768 + t];
      psum[(size_t)bcol * NB + brow * 256 + t] = s4;
    }
  } else {
    float* Cp = (float*)Cv + (unsigned long long)ksp * cstride;
    #pragma unroll
    for (int m = 0; m < 8; ++m)
      #pragma unroll
      for (int n = 0; n < 4; ++n)
        #pragma unroll
        for (int j = 0; j < 4; ++j)
          Cp[(size_t)(crow0 + m * 32 + j) * ldc + ccol0 + n * 16] = acc[m][n][j];
  }
}

// ---- scale: attn = E / s, s = sum of 32 col-block partials; also 1/s -------
__global__ void scale_kernel(const unsigned short* __restrict__ E,
                             const float* __restrict__ psum,
                             float* __restrict__ attn, float* __restrict__ sinv) {
  const int row = blockIdx.x, t = threadIdx.x;   // 256 thr
  __shared__ float sh;
  if (t < 64) {
    float p = (t < 32) ? psum[(size_t)t * NB + row] : 0.f;
    #pragma unroll
    for (int o = 16; o > 0; o >>= 1) p += __shfl_xor(p, o);
    if (t == 0) { sh = p; sinv[row] = 1.0f / p; }
  }
  __syncthreads();
  const float inv = 1.0f / sh;
  const unsigned short* erow = E + (size_t)row * NM;
  float* arow = attn + (size_t)row * NM;
  #pragma unroll
  for (int i = 0; i < 4; ++i) {
    u16x8 bv = ((const u16x8*)erow)[i * 256 + t];
    float4 f0, f1;
    #pragma unroll
    for (int j = 0; j < 8; ++j) {
      const float a = bf2f(bv[j]) * inv;
      if (j < 4) (&f0.x)[j] = a; else (&f1.x)[j - 4] = a;
    }
    const int e = (i * 256 + t) * 8;
    *(float4*)(arow + e) = f0;
    *(float4*)(arow + e + 4) = f1;
  }
}

// ---- reduce partials: mf = (sum_k part[k]) * sinv[row], S = 4 --------------
__global__ void reduce_kernel(const float4* __restrict__ part, float4* __restrict__ mf,
                              const float* __restrict__ sinv) {
  const size_t n4 = (size_t)NB * ND / 4;
  for (size_t i = (size_t)blockIdx.x * blockDim.x + threadIdx.x; i < n4;
       i += (size_t)gridDim.x * blockDim.x) {
    const float is = sinv[i >> 8];   // 256 float4 per row
    float4 s = part[i];
    #pragma unroll
    for (int k = 1; k < 4; ++k) {
      float4 p = part[(size_t)k * n4 + i];
      s.x += p.x; s.y += p.y; s.z += p.z; s.w += p.w;
    }
    s.x *= is; s.y *= is; s.z *= is; s.w *= is;
    mf[i] = s;
  }
}

extern "C" void kernel_launch(void* const* d_in, const int* in_sizes, int n_in,
                              void* d_out, int out_size, void* d_ws, size_t ws_size,
                              hipStream_t stream) {
  const float* q   = (const float*)d_in[0];
  const float* mem = (const float*)d_in[1];
  float* mf   = (float*)d_out;                       // [4096 x 1024]
  float* attn = (float*)d_out + (size_t)NB * ND;     // [4096 x 8192]
  char* ws = (char*)d_ws;
  unsigned short* qn   = (unsigned short*)(ws);                        // 8 MiB
  unsigned short* memn = (unsigned short*)(ws + ((size_t)8  << 20));   // 16 MiB
  unsigned short* memt = (unsigned short*)(ws + ((size_t)24 << 20));   // 16 MiB
  unsigned short* E    = (unsigned short*)(ws + ((size_t)40 << 20));   // 64 MiB
  float* psum          = (float*)(ws + ((size_t)104 << 20));           // 512 KiB
  float* sinv          = (float*)(ws + ((size_t)104 << 20) + (512 << 10)); // 16 KiB
  float* part          = (float*)(ws + ((size_t)105 << 20));           // 64 MiB

  hipFuncSetAttribute((const void*)gemmag<1>,
                      hipFuncAttributeMaxDynamicSharedMemorySize, 131072);
  hipFuncSetAttribute((const void*)gemmag<0>,
                      hipFuncAttributeMaxDynamicSharedMemorySize, 131072);

  hipLaunchKernelGGL(nrm_kernel, dim3(NM), dim3(256), 0, stream, mem, memn);
  hipLaunchKernelGGL(nrm_kernel, dim3(NB), dim3(256), 0, stream, q, qn);
  hipLaunchKernelGGL(tr_kernel, dim3(ND / 64, NM / 64), dim3(256), 0, stream, memn, memt);

  // E = exp(qn * memn^T) bf16 + psum : M=4096, N=8192, K=1024; 512 tiles.
  hipLaunchKernelGGL((gemmag<1>), dim3((NB / 256) * (NM / 256)), dim3(512), 131072, stream,
                     qn, memn, (void*)E, psum, ND, NM, NB / 256,
                     (NB / 256) * (NM / 256), ND, 0ULL);

  // attn = E / s (fp32 out) + sinv
  hipLaunchKernelGGL(scale_kernel, dim3(NB), dim3(256), 0, stream, E, psum, attn, sinv);

  // part[k] = E * memt^T (k-slice) : M=4096, N=1024, K=8192, S=4 (kchunk 2048)
  const int tps = (NB / 256) * (ND / 256);   // 64
  hipLaunchKernelGGL((gemmag<0>), dim3(tps * 4), dim3(512), 131072, stream,
                     E, memt, (void*)part, (float*)nullptr, NM, ND, NB / 256, tps, NM / 4,
                     (unsigned long long)NB * ND);
  hipLaunchKernelGGL(reduce_kernel, dim3(2048), dim3(256), 0, stream,
                     (const float4*)part, (float4*)mf, sinv);
}

// Round 14
// 187.194 us; speedup vs baseline: 1.2895x; 1.2230x over previous
//
#include <hip/hip_runtime.h>
#include <stdint.h>

#define NB 4096   // query rows
#define NM 8192   // memory rows
#define ND 1024   // feature dim

typedef __attribute__((ext_vector_type(8))) short bf16x8;
typedef __attribute__((ext_vector_type(4))) float f32x4;
typedef __attribute__((ext_vector_type(8))) unsigned short u16x8;
typedef __attribute__((ext_vector_type(4))) int i32x4;
typedef __attribute__((ext_vector_type(8))) int i32x8;

#define SCONE 0x7F7F7F7F   // four e8m0 scales = 2^0 (opsel-proof)

static __device__ __forceinline__ unsigned short f2bf(float f) {
  union { float f; uint32_t u; } v; v.f = f;
  uint32_t u = v.u;
  u += 0x7fffu + ((u >> 16) & 1u);   // RNE
  return (unsigned short)(u >> 16);
}
static __device__ __forceinline__ float bf2f(unsigned short b) {
  union { uint32_t u; float f; } v; v.u = ((uint32_t)b) << 16; return v.f;
}
// fp32 -> OCP e4m3fn, RNE, saturating (manual; no header dependency)
static __device__ __forceinline__ uint8_t f2fp8(float f) {
  union { float f; uint32_t u; } v; v.f = f;
  const uint8_t s = (uint8_t)((v.u >> 31) << 7);
  const float a = fabsf(f);
  if (a >= 448.f) return s | 0x7E;
  if (a < 0.0009765625f) return s;            // < 2^-10 -> 0
  const uint32_t u = v.u & 0x7FFFFFFFu;
  const int e = (int)(u >> 23) - 127;
  if (e < -6) {                                // subnormal: m * 2^-9
    int m = (int)rintf(a * 512.f);
    if (m >= 8) return s | 0x08;
    return s | (uint8_t)m;
  }
  const uint32_t r = u + 0x7FFFFu + ((u >> 20) & 1u);  // RNE to 3-bit mant
  const int e2 = (int)(r >> 23) - 127;
  if (e2 > 8) return s | 0x7E;
  return s | (uint8_t)((e2 + 7) << 3) | (uint8_t)((r >> 20) & 7u);
}

static __device__ __forceinline__ void gload_lds16(const void* g, void* l) {
  __builtin_amdgcn_global_load_lds(
      (__attribute__((address_space(1))) void*)g,
      (__attribute__((address_space(3))) void*)l, 16, 0, 0);
}

#define BAR()   __builtin_amdgcn_s_barrier()
#define LGKM0() asm volatile("s_waitcnt lgkmcnt(0)" ::: "memory")
#define VMC8()  asm volatile("s_waitcnt vmcnt(8)" ::: "memory")
#define VMC2()  asm volatile("s_waitcnt vmcnt(2)" ::: "memory")
#define VMC0()  asm volatile("s_waitcnt vmcnt(0)" ::: "memory")

// ---- normalize mem rows -> bf16 (memn) + fp8 (memn8) -----------------------
__global__ void nrm_m8(const float* __restrict__ x, unsigned short* __restrict__ ob,
                       uint8_t* __restrict__ o8) {
  const int row = blockIdx.x, t = threadIdx.x;
  const float4 v = ((const float4*)(x + (size_t)row * ND))[t];
  float ss = v.x * v.x + v.y * v.y + v.z * v.z + v.w * v.w;
  #pragma unroll
  for (int o = 32; o > 0; o >>= 1) ss += __shfl_xor(ss, o);
  __shared__ float red[4];
  if ((t & 63) == 0) red[t >> 6] = ss;
  __syncthreads();
  ss = (red[0] + red[1]) + (red[2] + red[3]);
  const float sc = 1.0f / fmaxf(sqrtf(ss), 1e-12f);
  ushort4 o4;
  o4.x = f2bf(v.x * sc); o4.y = f2bf(v.y * sc);
  o4.z = f2bf(v.z * sc); o4.w = f2bf(v.w * sc);
  ((ushort4*)(ob + (size_t)row * ND))[t] = o4;
  uchar4 c4;
  c4.x = f2fp8(v.x * sc); c4.y = f2fp8(v.y * sc);
  c4.z = f2fp8(v.z * sc); c4.w = f2fp8(v.w * sc);
  ((uchar4*)(o8 + (size_t)row * ND))[t] = c4;
}

// ---- normalize q rows -> fp8 only ------------------------------------------
__global__ void nrm_q8(const float* __restrict__ x, uint8_t* __restrict__ o8) {
  const int row = blockIdx.x, t = threadIdx.x;
  const float4 v = ((const float4*)(x + (size_t)row * ND))[t];
  float ss = v.x * v.x + v.y * v.y + v.z * v.z + v.w * v.w;
  #pragma unroll
  for (int o = 32; o > 0; o >>= 1) ss += __shfl_xor(ss, o);
  __shared__ float red[4];
  if ((t & 63) == 0) red[t >> 6] = ss;
  __syncthreads();
  ss = (red[0] + red[1]) + (red[2] + red[3]);
  const float sc = 1.0f / fmaxf(sqrtf(ss), 1e-12f);
  uchar4 c4;
  c4.x = f2fp8(v.x * sc); c4.y = f2fp8(v.y * sc);
  c4.z = f2fp8(v.z * sc); c4.w = f2fp8(v.w * sc);
  ((uchar4*)(o8 + (size_t)row * ND))[t] = c4;
}

// ---- transpose memn [8192x1024] bf16 -> memt [1024x8192] bf16 --------------
__global__ void tr_kernel(const unsigned short* __restrict__ memn, unsigned short* __restrict__ memt) {
  __shared__ unsigned short Ts[64][66];
  const int t = threadIdx.x;
  const int d0 = blockIdx.x * 64, m0 = blockIdx.y * 64;
  #pragma unroll
  for (int r = 0; r < 2; ++r) {
    const int lrow = r * 32 + (t >> 3);
    const int lcol = (t & 7) * 8;
    u16x8 v = *(const u16x8*)(memn + (size_t)(m0 + lrow) * ND + d0 + lcol);
    #pragma unroll
    for (int j = 0; j < 8; ++j) Ts[lcol + j][lrow] = v[j];
  }
  __syncthreads();
  #pragma unroll
  for (int r = 0; r < 2; ++r) {
    const int orow = r * 32 + (t >> 3);
    const int ocol = (t & 7) * 8;
    u16x8 o;
    #pragma unroll
    for (int j = 0; j < 8; ++j) o[j] = Ts[orow][ocol + j];
    *(u16x8*)(memt + (size_t)(d0 + orow) * NM + m0 + ocol) = o;
  }
}

// ====== GEMM1: 256x256, MX-fp8 K=128 MFMA, r10 ring schedule ================
// E = exp(A*B^T) bf16 + psum row-sums. A=qn8 [4096x1024]B, B=memn8 [8192x1024]B.
// BK=128 fp8 = 128-BYTE rows -> LDS geometry/staging/swizzle byte-identical to
// the r10 bf16 BK=64 kernel. K-tiles: 1024/128 = 8 (vs 16) -> per-tile fixed
// stalls halve; MFMA at 2x rate (mfma_scale 16x16x128, scales = 1.0).
// Frag: lane holds row=l&15, k-bytes lhi*32..+32 (two swizzled 16B ds_reads).
__global__ __launch_bounds__(512, 2) void gemm4x(
    const uint8_t* __restrict__ A, const uint8_t* __restrict__ B,
    unsigned short* __restrict__ E, float* __restrict__ psum,
    int ld, int ldc, int mt, int kchunk)
{
  extern __shared__ char smem[];   // [buf][A 32K | B 32K] x2 = 128 KiB
  const int t = threadIdx.x;
  const int w = t >> 6, l = t & 63;
  const int wr = w >> 2, wc = w & 3;
  const int nwg = gridDim.x, cpx = nwg >> 3;
  const int id = (blockIdx.x & 7) * cpx + (blockIdx.x >> 3);  // XCD swizzle
  const int brow = id % mt, bcol = id / mt;
  const int nt = kchunk >> 7;          // K-tiles of 128 (8; even)

  const int srow = l >> 3;                       // staging row-in-8-group
  const int scol = ((l & 7) ^ srow) << 4;        // pre-swizzled global col (B)
  const int lr = l & 15, lhi = l >> 4;
  const int swz = (l & 7) << 4;
  const int cb0 = (lhi * 32) ^ swz;              // frag lo 16B
  const int cb1 = (lhi * 32 + 16) ^ swz;         // frag hi 16B
  const int aoffr = (wr * 16 + lr) * 128;        // + m*4096
  const int boffr = (wc * 16 + lr) * 128;        // + nf*8192

  const uint8_t* Ab = A + (size_t)(brow * 256 + w * 8 + srow) * ld + scol;
  const uint8_t* Bb = B + (size_t)(bcol * 256 + w * 8 + srow) * ld + scol;

  auto stageA = [&](int p, int h, int tau) {     // one half-region = 2 gloads
    const int kt = (tau < nt ? tau : nt - 1) << 7;
    const uint8_t* g = Ab + (size_t)(h * 128) * ld + kt;
    char* d = smem + p * 65536 + h * 16384 + w * 1024;
    gload_lds16(g, d);
    gload_lds16(g + (size_t)64 * ld, d + 8192);
  };
  auto stageB = [&](int p, int h, int tau) {
    const int kt = (tau < nt ? tau : nt - 1) << 7;
    const uint8_t* g = Bb + (size_t)(h * 128) * ld + kt;
    char* d = smem + p * 65536 + 32768 + h * 16384 + w * 1024;
    gload_lds16(g, d);
    gload_lds16(g + (size_t)64 * ld, d + 8192);
  };
  auto ldA4 = [&](int p, int m, int c) -> i32x4 {
    return *(const i32x4*)(smem + p * 65536 + m * 4096 + aoffr + (c ? cb1 : cb0));
  };
  auto ldB4 = [&](int p, int nf, int c) -> i32x4 {
    return *(const i32x4*)(smem + p * 65536 + 32768 + nf * 8192 + boffr + (c ? cb1 : cb0));
  };

  f32x4 acc[8][4] = {};
  i32x8 alo[4], ahi[4], bloA[2], bloB[2], bhi[2];

  #define RDA4(DST, P, MB)                                                     \
    _Pragma("unroll")                                                          \
    for (int m_ = 0; m_ < 4; ++m_) {                                           \
      i32x4 lo_ = ldA4(P, (MB) + m_, 0), hi_ = ldA4(P, (MB) + m_, 1);          \
      i32x8 r_; r_[0]=lo_[0]; r_[1]=lo_[1]; r_[2]=lo_[2]; r_[3]=lo_[3];        \
      r_[4]=hi_[0]; r_[5]=hi_[1]; r_[6]=hi_[2]; r_[7]=hi_[3]; DST[m_] = r_; }
  #define RDB4(DST, P, NBASE)                                                  \
    _Pragma("unroll")                                                          \
    for (int n_ = 0; n_ < 2; ++n_) {                                           \
      i32x4 lo_ = ldB4(P, (NBASE) + n_, 0), hi_ = ldB4(P, (NBASE) + n_, 1);    \
      i32x8 r_; r_[0]=lo_[0]; r_[1]=lo_[1]; r_[2]=lo_[2]; r_[3]=lo_[3];        \
      r_[4]=hi_[0]; r_[5]=hi_[1]; r_[6]=hi_[2]; r_[7]=hi_[3]; DST[n_] = r_; }
  #define CL8(AF, BF, MO, NO)                                                  \
    __builtin_amdgcn_s_setprio(1);                                             \
    _Pragma("unroll")                                                          \
    for (int m_ = 0; m_ < 4; ++m_)                                             \
      _Pragma("unroll")                                                        \
      for (int n_ = 0; n_ < 2; ++n_)                                           \
        acc[(MO) + m_][(NO) + n_] =                                            \
            __builtin_amdgcn_mfma_scale_f32_16x16x128_f8f6f4(                  \
                AF[m_], BF[n_], acc[(MO) + m_][(NO) + n_],                     \
                0, 0, 0, SCONE, 0, SCONE);                                     \
    __builtin_amdgcn_s_setprio(0);

  // prologue: stage tiles 0,1; drain tile0; prime alo(0), bloA(0).
  stageA(0, 0, 0); stageA(0, 1, 0); stageB(0, 0, 0); stageB(0, 1, 0);
  stageA(1, 0, 1); stageA(1, 1, 1); stageB(1, 0, 1); stageB(1, 1, 1);
  VMC8();
  BAR();
  RDA4(alo, 0, 0);
  RDB4(bloA, 0, 0);

  const int niter = nt >> 1;
  for (int i = 0; i < niter; ++i) {
    const int t2 = 2 * i + 2, t3 = 2 * i + 3;
    // ===== tile T = 2i (buf 0, blo = bloA) =====
    LGKM0();
    CL8(alo, bloA, 0, 0);
    RDB4(bhi, 0, 2);
    BAR();
    LGKM0();
    CL8(alo, bhi, 0, 2);
    RDA4(ahi, 0, 4);
    stageB(0, 0, t2);
    VMC2();
    BAR();
    LGKM0();
    CL8(ahi, bhi, 4, 2);
    RDB4(bloB, 1, 0);
    stageB(0, 1, t2); stageA(0, 0, t2);
    BAR();
    LGKM0();
    CL8(ahi, bloA, 4, 0);
    RDA4(alo, 1, 0);
    stageA(0, 1, t2);
    BAR();
    // ===== tile T+1 (buf 1, blo = bloB) =====
    LGKM0();
    CL8(alo, bloB, 0, 0);
    RDB4(bhi, 1, 2);
    BAR();
    LGKM0();
    CL8(alo, bhi, 0, 2);
    RDA4(ahi, 1, 4);
    stageB(1, 0, t3);
    VMC2();
    BAR();
    LGKM0();
    CL8(ahi, bhi, 4, 2);
    RDB4(bloA, 0, 0);
    stageB(1, 1, t3); stageA(1, 0, t3);
    BAR();
    LGKM0();
    CL8(ahi, bloB, 4, 0);
    RDA4(alo, 0, 0);
    stageA(1, 1, t3);
    BAR();
  }
  #undef RDA4
  #undef RDB4
  #undef CL8

  // epilogue: E = exp(sim) bf16 + per-block row-sum partials.
  // C row = brow*256 + m*32 + wr*16 + lhi*4 + j; col = bcol*256 + n*64 + wc*16 + lr.
  const int crow0 = brow * 256 + wr * 16 + lhi * 4;
  const int ccol0 = bcol * 256 + wc * 16 + lr;
  float rs[8][4];
  #pragma unroll
  for (int m = 0; m < 8; ++m)
    #pragma unroll
    for (int j = 0; j < 4; ++j) rs[m][j] = 0.f;
  #pragma unroll
  for (int m = 0; m < 8; ++m)
    #pragma unroll
    for (int n = 0; n < 4; ++n)
      #pragma unroll
      for (int j = 0; j < 4; ++j) {
        const float e = __expf(acc[m][n][j]);
        rs[m][j] += e;
        E[(size_t)(crow0 + m * 32 + j) * ldc + ccol0 + n * 64] = f2bf(e);
      }
  #pragma unroll
  for (int m = 0; m < 8; ++m)
    #pragma unroll
    for (int j = 0; j < 4; ++j)
      #pragma unroll
      for (int o = 1; o < 16; o <<= 1) rs[m][j] += __shfl_xor(rs[m][j], o);
  VMC0();            // clamped in-flight stages still write smem
  __syncthreads();
  float* ls = (float*)smem;   // [wc][256 rows] = 4 KiB
  if (lr == 0) {
    #pragma unroll
    for (int m = 0; m < 8; ++m)
      #pragma unroll
      for (int j = 0; j < 4; ++j)
        ls[wc * 256 + wr * 16 + m * 32 + lhi * 4 + j] = rs[m][j];
  }
  __syncthreads();
  if (t < 256) {
    const float s4 = ls[t] + ls[256 + t] + ls[512 + t] + ls[768 + t];
    psum[(size_t)bcol * NB + brow * 256 + t] = s4;
  }
}

// ====== GEMM2: 256x256 bf16, r10 ring schedule, split-K fp32 partials =======
__global__ __launch_bounds__(512, 2) void gemm4r(
    const unsigned short* __restrict__ A, const unsigned short* __restrict__ B,
    float* __restrict__ C, int ld, int ldc, int mt, int tps, int kchunk,
    unsigned long long cstride)
{
  extern __shared__ char smem[];
  const int t = threadIdx.x;
  const int w = t >> 6, l = t & 63;
  const int wr = w >> 2, wc = w & 3;
  const int nwg = gridDim.x, cpx = nwg >> 3;
  const int id = (blockIdx.x & 7) * cpx + (blockIdx.x >> 3);
  const int ksp = id / tps, rem = id % tps;
  const int brow = rem % mt, bcol = rem / mt;
  const int k0 = ksp * kchunk;
  const int nt = kchunk >> 6;

  const int srow = l >> 3;
  const int scol = ((l & 7) ^ srow) << 3;
  const int lr = l & 15, lhi = l >> 4;
  const int swz = (l & 7) << 4;
  const int cbk0 = (lhi * 16) ^ swz;
  const int cbk1 = (64 + lhi * 16) ^ swz;
  const int aoffr = (wr * 16 + lr) * 128;
  const int boffr = (wc * 16 + lr) * 128;

  const unsigned short* Ab = A + (size_t)(brow * 256 + w * 8 + srow) * ld + k0 + scol;
  const unsigned short* Bb = B + (size_t)(bcol * 256 + w * 8 + srow) * ld + k0 + scol;

  auto stageA = [&](int p, int h, int tau) {
    const int kt = (tau < nt ? tau : nt - 1) << 6;
    const unsigned short* g = Ab + (size_t)(h * 128) * ld + kt;
    char* d = smem + p * 65536 + h * 16384 + w * 1024;
    gload_lds16(g, d);
    gload_lds16(g + (size_t)64 * ld, d + 8192);
  };
  auto stageB = [&](int p, int h, int tau) {
    const int kt = (tau < nt ? tau : nt - 1) << 6;
    const unsigned short* g = Bb + (size_t)(h * 128) * ld + kt;
    char* d = smem + p * 65536 + 32768 + h * 16384 + w * 1024;
    gload_lds16(g, d);
    gload_lds16(g + (size_t)64 * ld, d + 8192);
  };
  auto ldA = [&](int p, int m, int kk) -> bf16x8 {
    return *(const bf16x8*)(smem + p * 65536 + m * 4096 + aoffr + (kk ? cbk1 : cbk0));
  };
  auto ldB = [&](int p, int nf, int kk) -> bf16x8 {
    return *(const bf16x8*)(smem + p * 65536 + 32768 + nf * 8192 + boffr + (kk ? cbk1 : cbk0));
  };

  f32x4 acc[8][4] = {};
  bf16x8 alo[4][2], ahi[4][2], bloA[2][2], bloB[2][2], bhi[2][2];

  stageA(0, 0, 0); stageA(0, 1, 0); stageB(0, 0, 0); stageB(0, 1, 0);
  stageA(1, 0, 1); stageA(1, 1, 1); stageB(1, 0, 1); stageB(1, 1, 1);
  VMC8();
  BAR();
  #pragma unroll
  for (int m = 0; m < 4; ++m) { alo[m][0] = ldA(0, m, 0); alo[m][1] = ldA(0, m, 1); }
  #pragma unroll
  for (int n = 0; n < 2; ++n) { bloA[n][0] = ldB(0, n, 0); bloA[n][1] = ldB(0, n, 1); }

  #define CL(AF, BF, MO, NO)                                                   \
    __builtin_amdgcn_s_setprio(1);                                             \
    _Pragma("unroll")                                                          \
    for (int kk = 0; kk < 2; ++kk)                                             \
      _Pragma("unroll")                                                        \
      for (int m = 0; m < 4; ++m)                                              \
        _Pragma("unroll")                                                      \
        for (int n = 0; n < 2; ++n)                                            \
          acc[MO + m][NO + n] = __builtin_amdgcn_mfma_f32_16x16x32_bf16(       \
              AF[m][kk], BF[n][kk], acc[MO + m][NO + n], 0, 0, 0);             \
    __builtin_amdgcn_s_setprio(0);

  const int niter = nt >> 1;
  for (int i = 0; i < niter; ++i) {
    const int t2 = 2 * i + 2, t3 = 2 * i + 3;
    LGKM0();
    CL(alo, bloA, 0, 0);
    #pragma unroll
    for (int n = 0; n < 2; ++n) { bhi[n][0] = ldB(0, 2 + n, 0); bhi[n][1] = ldB(0, 2 + n, 1); }
    BAR();
    LGKM0();
    CL(alo, bhi, 0, 2);
    #pragma unroll
    for (int m = 0; m < 4; ++m) { ahi[m][0] = ldA(0, 4 + m, 0); ahi[m][1] = ldA(0, 4 + m, 1); }
    stageB(0, 0, t2);
    VMC2();
    BAR();
    LGKM0();
    CL(ahi, bhi, 4, 2);
    #pragma unroll
    for (int n = 0; n < 2; ++n) { bloB[n][0] = ldB(1, n, 0); bloB[n][1] = ldB(1, n, 1); }
    stageB(0, 1, t2); stageA(0, 0, t2);
    BAR();
    LGKM0();
    CL(ahi, bloA, 4, 0);
    #pragma unroll
    for (int m = 0; m < 4; ++m) { alo[m][0] = ldA(1, m, 0); alo[m][1] = ldA(1, m, 1); }
    stageA(0, 1, t2);
    BAR();
    LGKM0();
    CL(alo, bloB, 0, 0);
    #pragma unroll
    for (int n = 0; n < 2; ++n) { bhi[n][0] = ldB(1, 2 + n, 0); bhi[n][1] = ldB(1, 2 + n, 1); }
    BAR();
    LGKM0();
    CL(alo, bhi, 0, 2);
    #pragma unroll
    for (int m = 0; m < 4; ++m) { ahi[m][0] = ldA(1, 4 + m, 0); ahi[m][1] = ldA(1, 4 + m, 1); }
    stageB(1, 0, t3);
    VMC2();
    BAR();
    LGKM0();
    CL(ahi, bhi, 4, 2);
    #pragma unroll
    for (int n = 0; n < 2; ++n) { bloA[n][0] = ldB(0, n, 0); bloA[n][1] = ldB(0, n, 1); }
    stageB(1, 1, t3); stageA(1, 0, t3);
    BAR();
    LGKM0();
    CL(ahi, bloB, 4, 0);
    #pragma unroll
    for (int m = 0; m < 4; ++m) { alo[m][0] = ldA(0, m, 0); alo[m][1] = ldA(0, m, 1); }
    stageA(1, 1, t3);
    BAR();
  }
  #undef CL

  const int crow0 = brow * 256 + wr * 16 + lhi * 4;
  const int ccol0 = bcol * 256 + wc * 16 + lr;
  float* Cp = C + (unsigned long long)ksp * cstride;
  #pragma unroll
  for (int m = 0; m < 8; ++m)
    #pragma unroll
    for (int n = 0; n < 4; ++n)
      #pragma unroll
      for (int j = 0; j < 4; ++j)
        Cp[(size_t)(crow0 + m * 32 + j) * ldc + ccol0 + n * 64] = acc[m][n][j];
}

// ---- scale: attn = E / s; also 1/s -----------------------------------------
__global__ void scale_kernel(const unsigned short* __restrict__ E,
                             const float* __restrict__ psum,
                             float* __restrict__ attn, float* __restrict__ sinv) {
  const int row = blockIdx.x, t = threadIdx.x;
  __shared__ float sh;
  if (t < 64) {
    float p = (t < 32) ? psum[(size_t)t * NB + row] : 0.f;
    #pragma unroll
    for (int o = 16; o > 0; o >>= 1) p += __shfl_xor(p, o);
    if (t == 0) { sh = p; sinv[row] = 1.0f / p; }
  }
  __syncthreads();
  const float inv = 1.0f / sh;
  const unsigned short* erow = E + (size_t)row * NM;
  float* arow = attn + (size_t)row * NM;
  #pragma unroll
  for (int i = 0; i < 4; ++i) {
    u16x8 bv = ((const u16x8*)erow)[i * 256 + t];
    float4 f0, f1;
    #pragma unroll
    for (int j = 0; j < 8; ++j) {
      const float a = bf2f(bv[j]) * inv;
      if (j < 4) (&f0.x)[j] = a; else (&f1.x)[j - 4] = a;
    }
    const int e = (i * 256 + t) * 8;
    *(float4*)(arow + e) = f0;
    *(float4*)(arow + e + 4) = f1;
  }
}

// ---- reduce partials: mf = (sum_k part[k]) * sinv[row], S = 4 --------------
__global__ void reduce_kernel(const float4* __restrict__ part, float4* __restrict__ mf,
                              const float* __restrict__ sinv) {
  const size_t n4 = (size_t)NB * ND / 4;
  for (size_t i = (size_t)blockIdx.x * blockDim.x + threadIdx.x; i < n4;
       i += (size_t)gridDim.x * blockDim.x) {
    const float is = sinv[i >> 8];
    float4 s = part[i];
    #pragma unroll
    for (int k = 1; k < 4; ++k) {
      float4 p = part[(size_t)k * n4 + i];
      s.x += p.x; s.y += p.y; s.z += p.z; s.w += p.w;
    }
    s.x *= is; s.y *= is; s.z *= is; s.w *= is;
    mf[i] = s;
  }
}

extern "C" void kernel_launch(void* const* d_in, const int* in_sizes, int n_in,
                              void* d_out, int out_size, void* d_ws, size_t ws_size,
                              hipStream_t stream) {
  const float* q   = (const float*)d_in[0];
  const float* mem = (const float*)d_in[1];
  float* mf   = (float*)d_out;                       // [4096 x 1024]
  float* attn = (float*)d_out + (size_t)NB * ND;     // [4096 x 8192]
  char* ws = (char*)d_ws;
  // Layout (169 MiB total; qn8 overlaps part — disjoint lifetimes):
  uint8_t* memn8       = (uint8_t*)(ws);                               // 8 MiB
  unsigned short* memn = (unsigned short*)(ws + ((size_t)8  << 20));   // 16 MiB
  unsigned short* memt = (unsigned short*)(ws + ((size_t)24 << 20));   // 16 MiB
  unsigned short* E    = (unsigned short*)(ws + ((size_t)40 << 20));   // 64 MiB
  float* psum          = (float*)(ws + ((size_t)104 << 20));           // 512 KiB
  float* sinv          = (float*)(ws + ((size_t)104 << 20) + (512 << 10)); // 16 KiB
  float* part          = (float*)(ws + ((size_t)105 << 20));           // 64 MiB
  uint8_t* qn8         = (uint8_t*)(ws + ((size_t)105 << 20));         // 4 MiB (dead before GEMM2)

  hipFuncSetAttribute((const void*)gemm4x,
                      hipFuncAttributeMaxDynamicSharedMemorySize, 131072);
  hipFuncSetAttribute((const void*)gemm4r,
                      hipFuncAttributeMaxDynamicSharedMemorySize, 131072);

  hipLaunchKernelGGL(nrm_m8, dim3(NM), dim3(256), 0, stream, mem, memn, memn8);
  hipLaunchKernelGGL(nrm_q8, dim3(NB), dim3(256), 0, stream, q, qn8);
  hipLaunchKernelGGL(tr_kernel, dim3(ND / 64, NM / 64), dim3(256), 0, stream, memn, memt);

  // E = exp(qn8 * memn8^T) bf16 + psum : MX-fp8, M=4096, N=8192, K=1024.
  hipLaunchKernelGGL(gemm4x, dim3((NB / 256) * (NM / 256)), dim3(512), 131072, stream,
                     qn8, memn8, E, psum, ND, NM, NB / 256, ND);

  // attn = E / s (fp32 out) + sinv
  hipLaunchKernelGGL(scale_kernel, dim3(NB), dim3(256), 0, stream, E, psum, attn, sinv);

  // part[k] = E * memt^T (k-slice) : bf16, M=4096, N=1024, K=8192, S=4
  const int tps = (NB / 256) * (ND / 256);   // 64
  hipLaunchKernelGGL(gemm4r, dim3(tps * 4), dim3(512), 131072, stream,
                     E, memt, part, NM, ND, NB / 256, tps, NM / 4,
                     (unsigned long long)NB * ND);
  hipLaunchKernelGGL(reduce_kernel, dim3(2048), dim3(256), 0, stream,
                     (const float4*)part, (float4*)mf, sinv);
}